// Round 1
// baseline (853.513 us; speedup 1.0000x reference)
//
#include <hip/hip_runtime.h>
#include <math.h>

// Problem constants (match reference)
#define Bn    16
#define FCH   6
#define NPIX  262144          // 512*512
#define KC    8
#define NITERS 12
#define TEMP_INV (1.0f/0.15f)
#define EPSF  1e-6f

// Workspace layout (float offsets)
#define WS_SCALE 0                        // Bn*FCH = 96
#define WS_SHIFT 96                       // 96
#define WS_C     192                      // Bn*KC*FCH = 768
#define WS_C2    960                      // Bn*KC = 128
#define WS_ACCC  1088                     // 768
#define WS_ACCS  1856                     // 128  (ACCC..ACCS contiguous: 896 floats)

#define TPB 256
#define PPT 16                            // pixels per thread
// grid.x = NPIX/(TPB*PPT) = 64, grid.y = Bn

// ---------------- per-channel mean/std (unbiased), one block per (b,f) --------
__global__ __launch_bounds__(256) void stats_kernel(const float* __restrict__ feat,
                                                    float* __restrict__ ws) {
    const int bf = blockIdx.x;                         // b*FCH + f
    const float4* p = (const float4*)(feat + (size_t)bf * NPIX);
    float s = 0.f, ss = 0.f;
    for (int i = threadIdx.x; i < NPIX / 4; i += 256) {
        float4 v = p[i];
        s  += v.x + v.y + v.z + v.w;
        ss += v.x * v.x + v.y * v.y + v.z * v.z + v.w * v.w;
    }
    __shared__ float shs[256], shss[256];
    shs[threadIdx.x] = s; shss[threadIdx.x] = ss;
    __syncthreads();
    for (int st = 128; st > 0; st >>= 1) {
        if (threadIdx.x < st) {
            shs[threadIdx.x]  += shs[threadIdx.x + st];
            shss[threadIdx.x] += shss[threadIdx.x + st];
        }
        __syncthreads();
    }
    if (threadIdx.x == 0) {
        float sum = shs[0], sumsq = shss[0];
        float mean = sum / (float)NPIX;
        float var  = (sumsq - sum * mean) / (float)(NPIX - 1);   // unbiased (ddof=1)
        float sd   = sqrtf(fmaxf(var, 0.f));
        float scale = 1.f / fmaxf(sd, EPSF);                     // ref clips std, not var
        ws[WS_SCALE + bf] = scale;
        ws[WS_SHIFT + bf] = -mean * scale;
    }
}

// ---------------- gather initial centroids + zero accumulators ---------------
__global__ void init_kernel(const float* __restrict__ feat,
                            const int* __restrict__ idx,
                            float* __restrict__ ws) {
    const int t = threadIdx.x;                          // 128 threads
    // zero ACCC+ACCS (896 floats) — ws is poisoned 0xAA before every call
    for (int i = t; i < Bn * KC * FCH + Bn * KC; i += 128) ws[WS_ACCC + i] = 0.f;
    if (t < Bn * KC) {
        const int b = t / KC;
        const int n = idx[t];
        float c2 = 0.f;
        for (int f = 0; f < FCH; ++f) {
            const int bf = b * FCH + f;
            float v = fmaf(feat[(size_t)bf * NPIX + n], ws[WS_SCALE + bf], ws[WS_SHIFT + bf]);
            ws[WS_C + t * FCH + f] = v;
            c2 = fmaf(v, v, c2);
        }
        ws[WS_C2 + t] = c2;
    }
}

// ---------------- fused assignment pass (one iteration) ----------------------
// blockIdx.y = batch, blockIdx.x = pixel chunk. If last: write normalized S to out
// and skip centroid accumulation (matches reference: final S uses C after 11 updates).
__global__ __launch_bounds__(TPB) void assign_kernel(const float* __restrict__ feat,
                                                     float* __restrict__ ws,
                                                     float* __restrict__ out,
                                                     const int last) {
    const int b = blockIdx.y;
    const int t = threadIdx.x;

    __shared__ float sC[KC * FCH];
    __shared__ float sC2[KC];
    __shared__ float sSc[FCH], sSh[FCH];
    __shared__ float sBlk[KC * FCH + KC];

    if (t < KC * FCH)               sC[t]      = ws[WS_C + b * KC * FCH + t];
    if (t >= 64 && t < 64 + KC)     sC2[t-64]  = ws[WS_C2 + b * KC + (t - 64)];
    if (t >= 96 && t < 96 + FCH) {  sSc[t-96]  = ws[WS_SCALE + b * FCH + (t - 96)];
                                    sSh[t-96]  = ws[WS_SHIFT + b * FCH + (t - 96)]; }
    if (t < KC * FCH + KC)          sBlk[t] = 0.f;
    __syncthreads();

    float Cr[KC][FCH], c2r[KC], sc[FCH], sh[FCH];
#pragma unroll
    for (int k = 0; k < KC; ++k) {
        c2r[k] = sC2[k];
#pragma unroll
        for (int f = 0; f < FCH; ++f) Cr[k][f] = sC[k * FCH + f];
    }
#pragma unroll
    for (int f = 0; f < FCH; ++f) { sc[f] = sSc[f]; sh[f] = sSh[f]; }

    float accC[KC][FCH], accS[KC];
#pragma unroll
    for (int k = 0; k < KC; ++k) {
        accS[k] = 0.f;
#pragma unroll
        for (int f = 0; f < FCH; ++f) accC[k][f] = 0.f;
    }

    const float* fb = feat + (size_t)b * FCH * NPIX;
    const int base = blockIdx.x * (PPT * TPB);

    for (int j = 0; j < PPT; ++j) {
        const int n = base + j * TPB + t;
        float x[FCH]; float x2 = 0.f;
#pragma unroll
        for (int f = 0; f < FCH; ++f) {
            float v = fmaf(fb[(size_t)f * NPIX + n], sc[f], sh[f]);
            x[f] = v; x2 = fmaf(v, v, x2);
        }
        float p[KC]; float dmin = 3.4e38f;
#pragma unroll
        for (int k = 0; k < KC; ++k) {
            float xc = 0.f;
#pragma unroll
            for (int f = 0; f < FCH; ++f) xc = fmaf(x[f], Cr[k][f], xc);
            float d = fmaxf(x2 + c2r[k] - 2.f * xc, 0.f);   // same form as reference
            p[k] = d; dmin = fminf(dmin, d);
        }
        float sum = 0.f;
#pragma unroll
        for (int k = 0; k < KC; ++k) {
            float e = __expf((dmin - p[k]) * TEMP_INV);
            p[k] = e; sum += e;
        }
        const float inv = 1.0f / sum;   // softmax sums to 1 -> final renorm is this same division
        if (last) {
#pragma unroll
            for (int k = 0; k < KC; ++k)
                out[((size_t)(b * KC + k)) * NPIX + n] = p[k] * inv;
        } else {
#pragma unroll
            for (int k = 0; k < KC; ++k) {
                float sv = p[k] * inv;
                accS[k] += sv;
#pragma unroll
                for (int f = 0; f < FCH; ++f) accC[k][f] = fmaf(sv, x[f], accC[k][f]);
            }
        }
    }

    if (!last) {
        // wave(64)-level shuffle reduction of the 56 partial sums
#pragma unroll
        for (int k = 0; k < KC; ++k) {
#pragma unroll
            for (int off = 32; off > 0; off >>= 1) accS[k] += __shfl_down(accS[k], off, 64);
#pragma unroll
            for (int f = 0; f < FCH; ++f)
#pragma unroll
                for (int off = 32; off > 0; off >>= 1) accC[k][f] += __shfl_down(accC[k][f], off, 64);
        }
        if ((t & 63) == 0) {            // 4 wave leaders -> LDS accumulator
#pragma unroll
            for (int k = 0; k < KC; ++k) {
                atomicAdd(&sBlk[KC * FCH + k], accS[k]);
#pragma unroll
                for (int f = 0; f < FCH; ++f) atomicAdd(&sBlk[k * FCH + f], accC[k][f]);
            }
        }
        __syncthreads();
        if (t < KC * FCH)
            atomicAdd(&ws[WS_ACCC + b * KC * FCH + t], sBlk[t]);
        else if (t < KC * FCH + KC)
            atomicAdd(&ws[WS_ACCS + b * KC + (t - KC * FCH)], sBlk[t]);
    }
}

// ---------------- centroid update: C = accC / clip(accS,eps); re-zero acc ----
__global__ void update_kernel(float* __restrict__ ws) {
    const int b = blockIdx.x;
    const int t = threadIdx.x;                  // 64
    __shared__ float cn[KC * FCH];
    if (t < KC * FCH) {
        const int k = t / FCH;
        float denom = fmaxf(ws[WS_ACCS + b * KC + k], EPSF);
        float v = ws[WS_ACCC + b * KC * FCH + t] / denom;
        ws[WS_C + b * KC * FCH + t] = v;
        cn[t] = v;
        ws[WS_ACCC + b * KC * FCH + t] = 0.f;   // re-zero for next iteration
    }
    __syncthreads();
    if (t < KC) {
        float s = 0.f;
#pragma unroll
        for (int f = 0; f < FCH; ++f) s = fmaf(cn[t * FCH + f], cn[t * FCH + f], s);
        ws[WS_C2 + b * KC + t] = s;
        ws[WS_ACCS + b * KC + t] = 0.f;
    }
}

extern "C" void kernel_launch(void* const* d_in, const int* in_sizes, int n_in,
                              void* d_out, int out_size, void* d_ws, size_t ws_size,
                              hipStream_t stream) {
    const float* feat = (const float*)d_in[0];
    const int*   idx  = (const int*)d_in[1];
    float* out = (float*)d_out;
    float* ws  = (float*)d_ws;

    stats_kernel<<<Bn * FCH, 256, 0, stream>>>(feat, ws);
    init_kernel<<<1, 128, 0, stream>>>(feat, idx, ws);

    dim3 grid(NPIX / (PPT * TPB), Bn);          // 64 x 16 = 1024 blocks
    for (int it = 0; it < NITERS; ++it) {
        const int last = (it == NITERS - 1);
        assign_kernel<<<grid, TPB, 0, stream>>>(feat, ws, out, last);
        if (!last) update_kernel<<<Bn, 64, 0, stream>>>(ws);
    }
}

// Round 2
// 704.917 us; speedup vs baseline: 1.2108x; 1.2108x over previous
//
#include <hip/hip_runtime.h>
#include <math.h>

// Problem constants (match reference)
#define Bn    16
#define FCH   6
#define NPIX  262144          // 512*512
#define KC    8
#define NITERS 12
#define TEMP_INV (1.0f/0.15f)
#define EPSF  1e-6f

// Workspace layout (float offsets)
#define WS_SCALE 0                        // Bn*FCH = 96
#define WS_SHIFT 96                       // 96
#define WS_C     192                      // Bn*KC*FCH = 768
#define WS_C2    960                      // Bn*KC = 128
#define WS_ACCC  1088                     // 768
#define WS_ACCS  1856                     // 128  (ACCC..ACCS contiguous: 896 floats)
#define WS_PART  2048                     // 96*32 partial sums
#define WS_PART2 5120                     // 96*32 partial sumsq

#define TPB 256
#define PPT 16                            // pixels per thread
// assign grid: (NPIX/(TPB*PPT)=64, Bn=16) = 1024 blocks

// ---------------- stage A: partial per-channel sums, 3072 blocks -------------
// block = (bf, chunk): bf = blockIdx.x>>5 in [0,96), chunk = blockIdx.x&31.
// Each block reduces 8192 pixels (2048 float4) of one channel plane.
__global__ __launch_bounds__(256) void stats_partial(const float* __restrict__ feat,
                                                     float* __restrict__ ws) {
    const int bf = blockIdx.x >> 5;
    const int c  = blockIdx.x & 31;
    const float4* p = (const float4*)(feat + (size_t)bf * NPIX) + c * 2048;
    float s = 0.f, ss = 0.f;
    for (int i = threadIdx.x; i < 2048; i += 256) {
        float4 v = p[i];
        s  += v.x + v.y + v.z + v.w;
        ss += v.x * v.x + v.y * v.y + v.z * v.z + v.w * v.w;
    }
#pragma unroll
    for (int off = 32; off > 0; off >>= 1) {
        s  += __shfl_down(s,  off, 64);
        ss += __shfl_down(ss, off, 64);
    }
    __shared__ float sh[8];
    const int w = threadIdx.x >> 6;
    if ((threadIdx.x & 63) == 0) { sh[w] = s; sh[4 + w] = ss; }
    __syncthreads();
    if (threadIdx.x == 0) {
        s  = sh[0] + sh[1] + sh[2] + sh[3];
        ss = sh[4] + sh[5] + sh[6] + sh[7];
        ws[WS_PART  + blockIdx.x] = s;
        ws[WS_PART2 + blockIdx.x] = ss;
    }
}

// ------- stage B fused with init: finalize stats, zero acc, gather C0 --------
__global__ void init_kernel(const float* __restrict__ feat,
                            const int* __restrict__ idx,
                            float* __restrict__ ws) {
    const int t = threadIdx.x;                          // 128 threads
    // zero ACCC+ACCS (896 floats) — ws is poisoned 0xAA before every call
    for (int i = t; i < Bn * KC * FCH + Bn * KC; i += 128) ws[WS_ACCC + i] = 0.f;
    if (t < Bn * FCH) {                                 // finalize per-channel stats
        float s = 0.f, ss = 0.f;
        for (int c = 0; c < 32; ++c) {
            s  += ws[WS_PART  + t * 32 + c];
            ss += ws[WS_PART2 + t * 32 + c];
        }
        float mean = s / (float)NPIX;
        float var  = (ss - s * mean) / (float)(NPIX - 1);   // unbiased (ddof=1)
        float sd   = sqrtf(fmaxf(var, 0.f));
        float scale = 1.f / fmaxf(sd, EPSF);                // ref clips std, not var
        ws[WS_SCALE + t] = scale;
        ws[WS_SHIFT + t] = -mean * scale;
    }
    __syncthreads();
    // gather initial centroids: one thread per (b,k), Bn*KC = 128
    {
        const int b = t / KC;
        const int n = idx[t];
        float c2 = 0.f;
        for (int f = 0; f < FCH; ++f) {
            const int bf = b * FCH + f;
            float v = fmaf(feat[(size_t)bf * NPIX + n], ws[WS_SCALE + bf], ws[WS_SHIFT + bf]);
            ws[WS_C + t * FCH + f] = v;
            c2 = fmaf(v, v, c2);
        }
        ws[WS_C2 + t] = c2;
    }
}

// ---------------- fused assignment pass (one iteration) ----------------------
// LAST=0: accumulate S-weighted sums for the centroid update.
// LAST=1: write normalized S to out (reference semantics: final S uses the
//         centroids produced by the 11th update).
template <int LAST>
__global__ __launch_bounds__(TPB, 2) void assign_kernel(const float* __restrict__ feat,
                                                        float* __restrict__ ws,
                                                        float* __restrict__ out) {
    const int b = blockIdx.y;
    const int t = threadIdx.x;

    __shared__ float sC[KC * FCH];
    __shared__ float sC2[KC];
    __shared__ float sSc[FCH], sSh[FCH];
    __shared__ float sBlk[KC * FCH + KC];

    if (t < KC * FCH)               sC[t]      = ws[WS_C + b * KC * FCH + t];
    if (t >= 64 && t < 64 + KC)     sC2[t-64]  = ws[WS_C2 + b * KC + (t - 64)];
    if (t >= 96 && t < 96 + FCH) {  sSc[t-96]  = ws[WS_SCALE + b * FCH + (t - 96)];
                                    sSh[t-96]  = ws[WS_SHIFT + b * FCH + (t - 96)]; }
    if (t < KC * FCH + KC)          sBlk[t] = 0.f;
    __syncthreads();

    float Cr[KC][FCH], c2r[KC], sc[FCH], sh[FCH];
#pragma unroll
    for (int k = 0; k < KC; ++k) {
        c2r[k] = sC2[k];
#pragma unroll
        for (int f = 0; f < FCH; ++f) Cr[k][f] = sC[k * FCH + f];
    }
#pragma unroll
    for (int f = 0; f < FCH; ++f) { sc[f] = sSc[f]; sh[f] = sSh[f]; }

    const float4* fb4 = (const float4*)(feat + (size_t)b * FCH * NPIX);
    const int base4 = blockIdx.x * (PPT * TPB / 4);     // float4 units

    if (LAST) {
        float4* out4 = (float4*)out;
        for (int j = 0; j < PPT / 4; ++j) {
            const int i4 = base4 + j * TPB + t;
            float xs[4][FCH];
#pragma unroll
            for (int f = 0; f < FCH; ++f) {
                float4 v = fb4[f * (NPIX / 4) + i4];
                xs[0][f] = fmaf(v.x, sc[f], sh[f]);
                xs[1][f] = fmaf(v.y, sc[f], sh[f]);
                xs[2][f] = fmaf(v.z, sc[f], sh[f]);
                xs[3][f] = fmaf(v.w, sc[f], sh[f]);
            }
            float sv[KC][4];
#pragma unroll
            for (int px = 0; px < 4; ++px) {
                float x2 = 0.f;
#pragma unroll
                for (int f = 0; f < FCH; ++f) x2 = fmaf(xs[px][f], xs[px][f], x2);
                float p[KC]; float dmin = 3.4e38f;
#pragma unroll
                for (int k = 0; k < KC; ++k) {
                    float xc = 0.f;
#pragma unroll
                    for (int f = 0; f < FCH; ++f) xc = fmaf(xs[px][f], Cr[k][f], xc);
                    float d = fmaxf(x2 + c2r[k] - 2.f * xc, 0.f);
                    p[k] = d; dmin = fminf(dmin, d);
                }
                float sum = 0.f;
#pragma unroll
                for (int k = 0; k < KC; ++k) {
                    float e = __expf((dmin - p[k]) * TEMP_INV);
                    p[k] = e; sum += e;
                }
                const float inv = 1.0f / sum;
#pragma unroll
                for (int k = 0; k < KC; ++k) sv[k][px] = p[k] * inv;
            }
#pragma unroll
            for (int k = 0; k < KC; ++k)
                out4[((size_t)(b * KC + k)) * (NPIX / 4) + i4] =
                    make_float4(sv[k][0], sv[k][1], sv[k][2], sv[k][3]);
        }
        return;
    }

    float accC[KC][FCH], accS[KC];
#pragma unroll
    for (int k = 0; k < KC; ++k) {
        accS[k] = 0.f;
#pragma unroll
        for (int f = 0; f < FCH; ++f) accC[k][f] = 0.f;
    }

    for (int j = 0; j < PPT / 4; ++j) {
        const int i4 = base4 + j * TPB + t;
        float xs[4][FCH];
#pragma unroll
        for (int f = 0; f < FCH; ++f) {
            float4 v = fb4[f * (NPIX / 4) + i4];
            xs[0][f] = fmaf(v.x, sc[f], sh[f]);
            xs[1][f] = fmaf(v.y, sc[f], sh[f]);
            xs[2][f] = fmaf(v.z, sc[f], sh[f]);
            xs[3][f] = fmaf(v.w, sc[f], sh[f]);
        }
#pragma unroll
        for (int px = 0; px < 4; ++px) {
            float x2 = 0.f;
#pragma unroll
            for (int f = 0; f < FCH; ++f) x2 = fmaf(xs[px][f], xs[px][f], x2);
            float p[KC]; float dmin = 3.4e38f;
#pragma unroll
            for (int k = 0; k < KC; ++k) {
                float xc = 0.f;
#pragma unroll
                for (int f = 0; f < FCH; ++f) xc = fmaf(xs[px][f], Cr[k][f], xc);
                float d = fmaxf(x2 + c2r[k] - 2.f * xc, 0.f);
                p[k] = d; dmin = fminf(dmin, d);
            }
            float sum = 0.f;
#pragma unroll
            for (int k = 0; k < KC; ++k) {
                float e = __expf((dmin - p[k]) * TEMP_INV);
                p[k] = e; sum += e;
            }
            const float inv = 1.0f / sum;
#pragma unroll
            for (int k = 0; k < KC; ++k) {
                float s = p[k] * inv;
                accS[k] += s;
#pragma unroll
                for (int f = 0; f < FCH; ++f) accC[k][f] = fmaf(s, xs[px][f], accC[k][f]);
            }
        }
    }

    // wave(64)-level shuffle reduction of the 56 partial sums
#pragma unroll
    for (int k = 0; k < KC; ++k) {
#pragma unroll
        for (int off = 32; off > 0; off >>= 1) accS[k] += __shfl_down(accS[k], off, 64);
#pragma unroll
        for (int f = 0; f < FCH; ++f)
#pragma unroll
            for (int off = 32; off > 0; off >>= 1) accC[k][f] += __shfl_down(accC[k][f], off, 64);
    }
    if ((t & 63) == 0) {            // 4 wave leaders -> LDS accumulator
#pragma unroll
        for (int k = 0; k < KC; ++k) {
            atomicAdd(&sBlk[KC * FCH + k], accS[k]);
#pragma unroll
            for (int f = 0; f < FCH; ++f) atomicAdd(&sBlk[k * FCH + f], accC[k][f]);
        }
    }
    __syncthreads();
    if (t < KC * FCH)
        atomicAdd(&ws[WS_ACCC + b * KC * FCH + t], sBlk[t]);
    else if (t < KC * FCH + KC)
        atomicAdd(&ws[WS_ACCS + b * KC + (t - KC * FCH)], sBlk[t]);
}

// ---------------- centroid update: C = accC / clip(accS,eps); re-zero acc ----
__global__ void update_kernel(float* __restrict__ ws) {
    const int b = blockIdx.x;
    const int t = threadIdx.x;                  // 64
    __shared__ float cn[KC * FCH];
    if (t < KC * FCH) {
        const int k = t / FCH;
        float denom = fmaxf(ws[WS_ACCS + b * KC + k], EPSF);
        float v = ws[WS_ACCC + b * KC * FCH + t] / denom;
        ws[WS_C + b * KC * FCH + t] = v;
        cn[t] = v;
        ws[WS_ACCC + b * KC * FCH + t] = 0.f;   // re-zero for next iteration
    }
    __syncthreads();
    if (t < KC) {
        float s = 0.f;
#pragma unroll
        for (int f = 0; f < FCH; ++f) s = fmaf(cn[t * FCH + f], cn[t * FCH + f], s);
        ws[WS_C2 + b * KC + t] = s;
        ws[WS_ACCS + b * KC + t] = 0.f;
    }
}

extern "C" void kernel_launch(void* const* d_in, const int* in_sizes, int n_in,
                              void* d_out, int out_size, void* d_ws, size_t ws_size,
                              hipStream_t stream) {
    const float* feat = (const float*)d_in[0];
    const int*   idx  = (const int*)d_in[1];
    float* out = (float*)d_out;
    float* ws  = (float*)d_ws;

    stats_partial<<<Bn * FCH * 32, 256, 0, stream>>>(feat, ws);   // 3072 blocks
    init_kernel<<<1, 128, 0, stream>>>(feat, idx, ws);

    dim3 grid(NPIX / (PPT * TPB), Bn);          // 64 x 16 = 1024 blocks
    for (int it = 0; it < NITERS; ++it) {
        if (it == NITERS - 1)
            assign_kernel<1><<<grid, TPB, 0, stream>>>(feat, ws, out);
        else {
            assign_kernel<0><<<grid, TPB, 0, stream>>>(feat, ws, out);
            update_kernel<<<Bn, 64, 0, stream>>>(ws);
        }
    }
}

// Round 3
// 570.329 us; speedup vs baseline: 1.4965x; 1.2360x over previous
//
#include <hip/hip_runtime.h>
#include <math.h>

// Problem constants (match reference)
#define Bn    16
#define FCH   6
#define NPIX  262144          // 512*512
#define KC    8
#define NITERS 12
#define EPSF  1e-6f
// 2*log2(e)/TEMP : logits in exp2 domain
#define ALPHA2 19.235933878519512f

#if __has_builtin(__builtin_amdgcn_exp2f)
#define EXP2(x) __builtin_amdgcn_exp2f(x)
#else
#define EXP2(x) __expf((x) * 0.6931471805599453f)
#endif

// Workspace layout (float offsets)
#define WS_SCALE 0                        // Bn*FCH = 96
#define WS_SHIFT 96                       // 96
#define WS_C     192                      // Bn*KC*FCH = 768 (C0 only)
#define WS_PART  2048                     // 96*32 partial sums
#define WS_PART2 5120                     // 96*32 partial sumsq
#define WS_ACC0  8192                     // 3 buffers x Bn*64 floats (48 accC | 8 accS | pad)
#define ACCBUF_STRIDE 1024                // Bn*64

#define TPB 256
#define PPT 32                            // pixels per thread
// assign grid: (NPIX/(TPB*PPT)=32, Bn=16) = 512 blocks, co-resident at 2 blocks/CU

// ---------------- stage A: partial per-channel sums, 3072 blocks -------------
__global__ __launch_bounds__(256) void stats_partial(const float* __restrict__ feat,
                                                     float* __restrict__ ws) {
    const int bf = blockIdx.x >> 5;
    const int c  = blockIdx.x & 31;
    const float4* p = (const float4*)(feat + (size_t)bf * NPIX) + c * 2048;
    float s = 0.f, ss = 0.f;
    for (int i = threadIdx.x; i < 2048; i += 256) {
        float4 v = p[i];
        s  += v.x + v.y + v.z + v.w;
        ss += v.x * v.x + v.y * v.y + v.z * v.z + v.w * v.w;
    }
#pragma unroll
    for (int off = 32; off > 0; off >>= 1) {
        s  += __shfl_down(s,  off, 64);
        ss += __shfl_down(ss, off, 64);
    }
    __shared__ float sh[8];
    const int w = threadIdx.x >> 6;
    if ((threadIdx.x & 63) == 0) { sh[w] = s; sh[4 + w] = ss; }
    __syncthreads();
    if (threadIdx.x == 0) {
        s  = sh[0] + sh[1] + sh[2] + sh[3];
        ss = sh[4] + sh[5] + sh[6] + sh[7];
        ws[WS_PART  + blockIdx.x] = s;
        ws[WS_PART2 + blockIdx.x] = ss;
    }
}

// ------- stage B: finalize stats, zero acc buffer 0, gather C0 ---------------
__global__ void init_kernel(const float* __restrict__ feat,
                            const int* __restrict__ idx,
                            float* __restrict__ ws) {
    const int t = threadIdx.x;                          // 128 threads
    for (int i = t; i < ACCBUF_STRIDE; i += 128) ws[WS_ACC0 + i] = 0.f;  // buf0
    if (t < Bn * FCH) {
        float s = 0.f, ss = 0.f;
        for (int c = 0; c < 32; ++c) {
            s  += ws[WS_PART  + t * 32 + c];
            ss += ws[WS_PART2 + t * 32 + c];
        }
        float mean = s / (float)NPIX;
        float var  = (ss - s * mean) / (float)(NPIX - 1);   // unbiased (ddof=1)
        float sd   = sqrtf(fmaxf(var, 0.f));
        float scale = 1.f / fmaxf(sd, EPSF);                // ref clips std, not var
        ws[WS_SCALE + t] = scale;
        ws[WS_SHIFT + t] = -mean * scale;
    }
    __syncthreads();
    {   // gather initial (standardized) centroids: thread t = (b,k), Bn*KC = 128
        const int b = t / KC;
        const int n = idx[t];
        for (int f = 0; f < FCH; ++f) {
            const int bf = b * FCH + f;
            float v = fmaf(feat[(size_t)bf * NPIX + n], ws[WS_SCALE + bf], ws[WS_SHIFT + bf]);
            ws[WS_C + t * FCH + f] = v;
        }
    }
}

// ---------------- fused assignment pass (one iteration) ----------------------
// Preamble: build centroids from accRead (or C0 when first), convert to the
// affine logit form  logit2_k = sum_f raw_f*W_kf + bias_k  (exp2 domain; the
// x^2 term is softmax-invariant and dropped; clamp @0 is fp-noise only).
// Accumulation is in RAW pixel space; converted back when folded in next iter.
template <int LAST>
__global__ __launch_bounds__(TPB, 2) void assign_kernel(const float* __restrict__ feat,
                                                        const float* __restrict__ ws,
                                                        float* __restrict__ out,
                                                        float* __restrict__ accAdd,
                                                        const float* __restrict__ accRead,
                                                        float* __restrict__ accZero,
                                                        const int first) {
    const int b = blockIdx.y;
    const int t = threadIdx.x;

    __shared__ float sWb[KC * FCH + KC];       // 48 weights + 8 biases
    __shared__ float sBlk[KC * FCH + KC];

    if (t < KC) {
        float sc[FCH], sh[FCH], C[FCH];
#pragma unroll
        for (int f = 0; f < FCH; ++f) {
            sc[f] = ws[WS_SCALE + b * FCH + f];
            sh[f] = ws[WS_SHIFT + b * FCH + f];
        }
        if (first) {
#pragma unroll
            for (int f = 0; f < FCH; ++f) C[f] = ws[WS_C + (b * KC + t) * FCH + f];
        } else {
            float as  = accRead[b * 64 + 48 + t];
            float inv = 1.f / fmaxf(as, EPSF);
#pragma unroll
            for (int f = 0; f < FCH; ++f)
                C[f] = (sc[f] * accRead[b * 64 + t * FCH + f] + sh[f] * as) * inv;
        }
        float c2 = 0.f, sd = 0.f;
#pragma unroll
        for (int f = 0; f < FCH; ++f) {
            c2 = fmaf(C[f], C[f], c2);
            sd = fmaf(sh[f], C[f], sd);
            sWb[t * FCH + f] = ALPHA2 * sc[f] * C[f];
        }
        sWb[KC * FCH + t] = ALPHA2 * sd - 0.5f * ALPHA2 * c2;
    }
    if (!LAST) {
        if (t < KC * FCH + KC) sBlk[t] = 0.f;
        if (blockIdx.x == 0 && t < 64) accZero[b * 64 + t] = 0.f;   // prep iter+1
    }
    __syncthreads();

    float W[KC][FCH], bias[KC];
#pragma unroll
    for (int k = 0; k < KC; ++k) {
        bias[k] = sWb[KC * FCH + k];
#pragma unroll
        for (int f = 0; f < FCH; ++f) W[k][f] = sWb[k * FCH + f];
    }

    const float4* fb4 = (const float4*)(feat + (size_t)b * FCH * NPIX);
    const int base4 = blockIdx.x * (PPT * TPB / 4);     // float4 units

    float accC[KC][FCH], accS[KC];
    if (!LAST) {
#pragma unroll
        for (int k = 0; k < KC; ++k) {
            accS[k] = 0.f;
#pragma unroll
            for (int f = 0; f < FCH; ++f) accC[k][f] = 0.f;
        }
    }

    for (int j = 0; j < PPT / 4; ++j) {
        const int i4 = base4 + j * TPB + t;
        float rr[FCH][4];
#pragma unroll
        for (int f = 0; f < FCH; ++f) {
            float4 v = fb4[f * (NPIX / 4) + i4];
            rr[f][0] = v.x; rr[f][1] = v.y; rr[f][2] = v.z; rr[f][3] = v.w;
        }
        float sv[KC][4];
#pragma unroll
        for (int px = 0; px < 4; ++px) {
            float l[KC];
#pragma unroll
            for (int k = 0; k < KC; ++k) {
                float v = bias[k];
#pragma unroll
                for (int f = 0; f < FCH; ++f) v = fmaf(rr[f][px], W[k][f], v);
                l[k] = v;
            }
            float m = l[0];
#pragma unroll
            for (int k = 1; k < KC; ++k) m = fmaxf(m, l[k]);
            float e[KC]; float sum = 0.f;
#pragma unroll
            for (int k = 0; k < KC; ++k) { e[k] = EXP2(l[k] - m); sum += e[k]; }
            const float inv = 1.0f / sum;
            if (LAST) {
#pragma unroll
                for (int k = 0; k < KC; ++k) sv[k][px] = e[k] * inv;
            } else {
#pragma unroll
                for (int k = 0; k < KC; ++k) {
                    float s = e[k] * inv;
                    accS[k] += s;
#pragma unroll
                    for (int f = 0; f < FCH; ++f) accC[k][f] = fmaf(s, rr[f][px], accC[k][f]);
                }
            }
        }
        if (LAST) {
            float4* out4 = (float4*)out;
#pragma unroll
            for (int k = 0; k < KC; ++k)
                out4[((size_t)(b * KC + k)) * (NPIX / 4) + i4] =
                    make_float4(sv[k][0], sv[k][1], sv[k][2], sv[k][3]);
        }
    }

    if (!LAST) {
        // wave(64) shuffle reduction of 56 partials -> LDS -> global atomics
#pragma unroll
        for (int k = 0; k < KC; ++k) {
#pragma unroll
            for (int off = 32; off > 0; off >>= 1) accS[k] += __shfl_down(accS[k], off, 64);
#pragma unroll
            for (int f = 0; f < FCH; ++f)
#pragma unroll
                for (int off = 32; off > 0; off >>= 1) accC[k][f] += __shfl_down(accC[k][f], off, 64);
        }
        if ((t & 63) == 0) {            // 4 wave leaders
#pragma unroll
            for (int k = 0; k < KC; ++k) {
                atomicAdd(&sBlk[KC * FCH + k], accS[k]);
#pragma unroll
                for (int f = 0; f < FCH; ++f) atomicAdd(&sBlk[k * FCH + f], accC[k][f]);
            }
        }
        __syncthreads();
        if (t < KC * FCH)
            atomicAdd(&accAdd[b * 64 + t], sBlk[t]);
        else if (t < KC * FCH + KC)
            atomicAdd(&accAdd[b * 64 + 48 + (t - KC * FCH)], sBlk[t]);
    }
}

extern "C" void kernel_launch(void* const* d_in, const int* in_sizes, int n_in,
                              void* d_out, int out_size, void* d_ws, size_t ws_size,
                              hipStream_t stream) {
    const float* feat = (const float*)d_in[0];
    const int*   idx  = (const int*)d_in[1];
    float* out = (float*)d_out;
    float* ws  = (float*)d_ws;

    stats_partial<<<Bn * FCH * 32, 256, 0, stream>>>(feat, ws);   // 3072 blocks
    init_kernel<<<1, 128, 0, stream>>>(feat, idx, ws);            // zeroes buf0

    dim3 grid(NPIX / (PPT * TPB), Bn);          // 32 x 16 = 512 blocks
    for (int it = 0; it < NITERS; ++it) {
        float*       bufA = ws + WS_ACC0 + (it % 3)       * ACCBUF_STRIDE;  // add
        const float* bufR = ws + WS_ACC0 + ((it + 2) % 3) * ACCBUF_STRIDE;  // read (it-1)
        float*       bufZ = ws + WS_ACC0 + ((it + 1) % 3) * ACCBUF_STRIDE;  // zero (it+1)
        if (it == NITERS - 1)
            assign_kernel<1><<<grid, TPB, 0, stream>>>(feat, ws, out, nullptr, bufR, nullptr, 0);
        else
            assign_kernel<0><<<grid, TPB, 0, stream>>>(feat, ws, out, bufA, bufR, bufZ, it == 0);
    }
}